// Round 5
// baseline (305.675 us; speedup 1.0000x reference)
//
#include <hip/hip_runtime.h>

typedef __bf16 bf16;
typedef bf16 bf16x8 __attribute__((ext_vector_type(8)));
typedef float f32x4 __attribute__((ext_vector_type(4)));

#define B_ 4
#define T_ 4096
#define C_ 1024
#define NCH 16
#define EPS_ 1e-6f

typedef __attribute__((address_space(1))) const void* as1p;
typedef __attribute__((address_space(3))) void* as3p;

// ---------------- cast f32 -> bf16 (vectorized, 8/thread) ----------------
__global__ void cast_kernel(const float* __restrict__ in, bf16* __restrict__ out, int n8) {
  int i = blockIdx.x * blockDim.x + threadIdx.x;
  int stride = gridDim.x * blockDim.x;
  for (; i < n8; i += stride) {
    const float4* p = (const float4*)(in + (size_t)i * 8);
    float4 v0 = p[0];
    float4 v1 = p[1];
    bf16x8 o;
    o[0] = (bf16)v0.x; o[1] = (bf16)v0.y; o[2] = (bf16)v0.z; o[3] = (bf16)v0.w;
    o[4] = (bf16)v1.x; o[5] = (bf16)v1.y; o[6] = (bf16)v1.z; o[7] = (bf16)v1.w;
    *(bf16x8*)(out + (size_t)i * 8) = o;
  }
}

// ---------------- deep-pipelined NT GEMM: C = A[M][K] * B[N][K]^T ----------------
// BM=256 BN=128 BK=32, 512 thr (8 waves, wave tile 64x64), 6 LDS buffers (144KB),
// 5-tile-ahead staging, vmcnt(9) gate, register double-buffered frags, ONE barrier/step.
#define BM 256
#define BN 128
#define BK 32
#define KD 1024
#define NT (KD / BK)                  // 32
#define ABYT (BM * BK * 2)            // 16384
#define BUFB ((BM + BN) * BK * 2)     // 24576
#define SMEMB (6 * BUFB)              // 147456

// One pipeline step: compute tile T from CUR regs, read tile T+1 into NXT regs,
// stage tile T+5, gate vmcnt so tile T+2 is landed at the barrier.
#define GSTEP(CURA, CURB, NXTA, NXTB, T)                                                   \
  do {                                                                                     \
    const bool pf = (T) + 5 < NT;                                                          \
    if (pf) {                                                                              \
      const int ko = ((T) + 5) * BK;                                                       \
      __builtin_amdgcn_global_load_lds((as1p)(pA0 + ko), (as3p)(smem + sb + tid * 16), 16, 0, 0);          \
      __builtin_amdgcn_global_load_lds((as1p)(pA1 + ko), (as3p)(smem + sb + 8192 + tid * 16), 16, 0, 0);   \
      __builtin_amdgcn_global_load_lds((as1p)(pB0 + ko), (as3p)(smem + sb + 16384 + tid * 16), 16, 0, 0);  \
    }                                                                                      \
    {                                                                                      \
      const bf16* Ab = (const bf16*)(smem + rb);                                           \
      const bf16* Bb = (const bf16*)(smem + rb + ABYT);                                    \
      _Pragma("unroll") for (int mi = 0; mi < 4; mi++)                                     \
          NXTA[mi] = *(const bf16x8*)(Ab + (wm * 64 + mi * 16 + fr) * 32 + fsw);           \
      _Pragma("unroll") for (int nj = 0; nj < 4; nj++)                                     \
          NXTB[nj] = *(const bf16x8*)(Bb + (wn * 64 + nj * 16 + fr) * 32 + fsw);           \
    }                                                                                      \
    __builtin_amdgcn_s_setprio(1);                                                         \
    _Pragma("unroll") for (int mi = 0; mi < 4; mi++)                                       \
        _Pragma("unroll") for (int nj = 0; nj < 4; nj++)                                   \
            acc[mi][nj] = __builtin_amdgcn_mfma_f32_16x16x32_bf16(CURA[mi], CURB[nj], acc[mi][nj], 0, 0, 0); \
    __builtin_amdgcn_s_setprio(0);                                                         \
    asm volatile("s_waitcnt lgkmcnt(0)" ::: "memory");                                     \
    if (pf) asm volatile("s_waitcnt vmcnt(9)" ::: "memory");                               \
    else    asm volatile("s_waitcnt vmcnt(0)" ::: "memory");                               \
    __builtin_amdgcn_s_barrier();                                                          \
    __builtin_amdgcn_sched_barrier(0);                                                     \
    rb += BUFB; if (rb >= SMEMB) rb -= SMEMB;                                              \
    sb += BUFB; if (sb >= SMEMB) sb -= SMEMB;                                              \
  } while (0)

template <int MODE>
__global__ __launch_bounds__(512, 1) void gemm5(
    const bf16* __restrict__ A, const bf16* __restrict__ Bm,
    void* __restrict__ Cout, const float* __restrict__ bias,
    int M, int N, int tiles_n) {
  extern __shared__ char smem[];
  const int tid = threadIdx.x;
  const int l = tid & 63;
  const int w = tid >> 6;
  const int wm = w >> 1;   // 0..3 (M 4x64)
  const int wn = w & 1;    // 0..1 (N 2x64)

  // T1: XCD-aware block swizzle (grids are multiples of 8)
  const int cpx = gridDim.x >> 3;
  const int bid = (blockIdx.x & 7) * cpx + (blockIdx.x >> 3);
  const int tm = (bid / tiles_n) * BM;
  const int tn = (bid % tiles_n) * BN;

  // staging: 4 lanes/row (64B row); content at (row,slot) = chunk slot^((row>>1)&3)
  const int srow = tid >> 2;                        // 0..127
  const int g8 = ((tid & 3) ^ ((tid >> 3) & 3)) * 8;  // ((srow>>1)&3) == (tid>>3)&3

  const bf16* pA0 = A + (size_t)(tm + srow) * KD + g8;
  const bf16* pA1 = A + (size_t)(tm + 128 + srow) * KD + g8;
  const bf16* pB0 = Bm + (size_t)(tn + srow) * KD + g8;

  // fragment read: row = base + fr; slot = fc ^ ((fr>>1)&3)  -> 2 lanes/bank (free)
  const int fr = l & 15;
  const int fc = l >> 4;
  const int fsw = (fc ^ ((fr >> 1) & 3)) * 8;

  f32x4 acc[4][4] = {};
  bf16x8 afA[4], bfA[4], afB[4], bfB[4];

  // prologue: stage tiles 0..4
#pragma unroll
  for (int kt = 0; kt < 5; kt++) {
    __builtin_amdgcn_global_load_lds((as1p)(pA0 + kt * BK), (as3p)(smem + kt * BUFB + tid * 16), 16, 0, 0);
    __builtin_amdgcn_global_load_lds((as1p)(pA1 + kt * BK), (as3p)(smem + kt * BUFB + 8192 + tid * 16), 16, 0, 0);
    __builtin_amdgcn_global_load_lds((as1p)(pB0 + kt * BK), (as3p)(smem + kt * BUFB + 16384 + tid * 16), 16, 0, 0);
  }
  asm volatile("s_waitcnt vmcnt(9)" ::: "memory");  // tiles 0,1 landed
  __builtin_amdgcn_s_barrier();
  __builtin_amdgcn_sched_barrier(0);

  // preload CUR = tile 0 (buffer 0)
  {
    const bf16* Ab = (const bf16*)(smem);
    const bf16* Bb = (const bf16*)(smem + ABYT);
#pragma unroll
    for (int mi = 0; mi < 4; mi++)
      afA[mi] = *(const bf16x8*)(Ab + (wm * 64 + mi * 16 + fr) * 32 + fsw);
#pragma unroll
    for (int nj = 0; nj < 4; nj++)
      bfA[nj] = *(const bf16x8*)(Bb + (wn * 64 + nj * 16 + fr) * 32 + fsw);
  }

  int rb = BUFB;          // body at step t reads tile t+1
  int sb = 5 * BUFB;      // body at step t stages tile t+5
  for (int t = 0; t < NT; t += 2) {
    GSTEP(afA, bfA, afB, bfB, t);
    GSTEP(afB, bfB, afA, bfA, t + 1);
  }

  // ---------------- epilogue: C/D col = lane&15, row = (lane>>4)*4 + r ----------------
  const int crow0 = tm + wm * 64 + (l >> 4) * 4;
  const int ccol0 = tn + wn * 64 + (l & 15);
  if (MODE == 0) {
    bf16* Cq = (bf16*)Cout;
#pragma unroll
    for (int mi = 0; mi < 4; mi++)
#pragma unroll
      for (int nj = 0; nj < 4; nj++) {
        const int col = ccol0 + nj * 16;
        const bool isqk = (col < 2 * C_);
#pragma unroll
        for (int r = 0; r < 4; r++) {
          const int row = crow0 + mi * 16 + r;
          float v = acc[mi][nj][r];
          if (isqk) v = (v > 0.f) ? (v + 1.0f) : __expf(v);
          Cq[(size_t)row * N + col] = (bf16)v;
        }
      }
  } else {
    float* Cf = (float*)Cout;
#pragma unroll
    for (int mi = 0; mi < 4; mi++)
#pragma unroll
      for (int nj = 0; nj < 4; nj++) {
        const int col = ccol0 + nj * 16;
        const float bv = bias[col];
#pragma unroll
        for (int r = 0; r < 4; r++) {
          const int row = crow0 + mi * 16 + r;
          Cf[(size_t)row * N + col] = acc[mi][nj][r] + bv;
        }
      }
  }
}

// ---------------- kv partial: kv[b,h,d,m] = sum_n k[b,n,h,d]*v[b,n,h,m] ----------------
__global__ __launch_bounds__(256) void kv_kernel(const bf16* __restrict__ qkv, float* __restrict__ partial) {
  const int bh = blockIdx.x & 63;
  const int ch = blockIdx.x >> 6;
  const int b = bh >> 4;
  const int h = bh & 15;
  const int tid = threadIdx.x;
  const int d = tid & 63;
  const int mb = tid >> 6;

  __shared__ float kb[8][64];
  __shared__ float vb[8][64];

  float acc[16] = {};
  float ks = 0.f;

  const int Tc = T_ / NCH;  // 256
  const int n0 = ch * Tc;

  for (int nb = 0; nb < Tc; nb += 8) {
    __syncthreads();
#pragma unroll
    for (int i = 0; i < 4; i++) {
      int q = tid * 4 + i;
      int nn = q >> 7;
      int r = q & 127;
      const bf16* rowp = qkv + (size_t)(b * T_ + n0 + nb + nn) * 3072 + C_ + h * 64;
      float val = (float)rowp[(r < 64) ? r : (C_ + r - 64)];
      if (r < 64) kb[nn][r] = val;
      else vb[nn][r - 64] = val;
    }
    __syncthreads();
#pragma unroll
    for (int nn = 0; nn < 8; nn++) {
      float kd = kb[nn][d];
      if (mb == 0) ks += kd;
#pragma unroll
      for (int j = 0; j < 16; j++)
        acc[j] += kd * vb[nn][mb * 16 + j];
    }
  }

  float* p = partial + (size_t)(ch * 64 + bh) * 4160;
#pragma unroll
  for (int j = 0; j < 16; j++)
    p[d * 64 + mb * 16 + j] = acc[j];
  if (mb == 0) p[4096 + d] = ks;
}

// ---------------- reduce partials -> kvb bf16 [bh][80][64] ----------------
__global__ void kv_reduce_b(const float* __restrict__ partial, bf16* __restrict__ kvb) {
  int i = blockIdx.x * blockDim.x + threadIdx.x;
  if (i >= 64 * 80 * 64) return;
  int d = i & 63;
  int row = (i >> 6) % 80;
  int bh = i / (80 * 64);
  float outv = 0.f;
  if (row < 64) {
    float s = 0.f;
#pragma unroll
    for (int ch = 0; ch < NCH; ch++)
      s += partial[(size_t)(ch * 64 + bh) * 4160 + d * 64 + row];
    kvb[(size_t)bh * 5120 + row * 64 + d] = (bf16)s;
    return;
  } else if (row < 66) {
    float ks = 0.f;
#pragma unroll
    for (int ch = 0; ch < NCH; ch++)
      ks += partial[(size_t)(ch * 64 + bh) * 4160 + 4096 + d];
    bf16 hi = (bf16)ks;
    outv = (row == 64) ? (float)hi : (ks - (float)hi);
  }
  kvb[(size_t)bh * 5120 + row * 64 + d] = (bf16)outv;
}

// ---------------- attn out via MFMA ----------------
__global__ __launch_bounds__(256) void attn_mfma(const bf16* __restrict__ qkv,
                                                 const bf16* __restrict__ kvb,
                                                 bf16* __restrict__ attn) {
  const int bh = blockIdx.x >> 4;
  const int tch = blockIdx.x & 15;
  const int b = bh >> 4;
  const int h = bh & 15;
  const int lane = threadIdx.x & 63;
  const int wave = threadIdx.x >> 6;
  const int t0 = tch * 256 + wave * 64;

  const bf16* kvp = kvb + (size_t)bh * 5120;
  bf16x8 bfrag[5][2];
#pragma unroll
  for (int j = 0; j < 5; j++)
#pragma unroll
    for (int kk = 0; kk < 2; kk++)
      bfrag[j][kk] = *(const bf16x8*)(kvp + (j * 16 + (lane & 15)) * 64 + kk * 32 + (lane >> 4) * 8);

  f32x4 acc[4][5] = {};
#pragma unroll
  for (int i = 0; i < 4; i++) {
    const int t = t0 + i * 16 + (lane & 15);
    const bf16* qp = qkv + (size_t)(b * T_ + t) * 3072 + h * 64 + (lane >> 4) * 8;
    bf16x8 a0 = *(const bf16x8*)qp;
    bf16x8 a1 = *(const bf16x8*)(qp + 32);
#pragma unroll
    for (int j = 0; j < 5; j++) {
      acc[i][j] = __builtin_amdgcn_mfma_f32_16x16x32_bf16(a0, bfrag[j][0], acc[i][j], 0, 0, 0);
      acc[i][j] = __builtin_amdgcn_mfma_f32_16x16x32_bf16(a1, bfrag[j][1], acc[i][j], 0, 0, 0);
    }
  }

#pragma unroll
  for (int i = 0; i < 4; i++) {
#pragma unroll
    for (int r = 0; r < 4; r++) {
      float hi = __shfl(acc[i][4][r], (lane & 48));
      float lo = __shfl(acc[i][4][r], (lane & 48) + 1);
      float inv = 1.0f / (hi + lo + EPS_);
      const int t = t0 + i * 16 + (lane >> 4) * 4 + r;
      bf16* op = attn + (size_t)(b * T_ + t) * 1024 + h * 64 + (lane & 15);
#pragma unroll
      for (int j = 0; j < 4; j++)
        op[j * 16] = (bf16)(acc[i][j][r] * inv);
    }
  }
}

// ---------------- launch ----------------
extern "C" void kernel_launch(void* const* d_in, const int* in_sizes, int n_in,
                              void* d_out, int out_size, void* d_ws, size_t ws_size,
                              hipStream_t stream) {
  const float* x = (const float*)d_in[0];
  const float* Wqkv = (const float*)d_in[1];
  const float* Wproj = (const float*)d_in[2];
  const float* bproj = (const float*)d_in[3];
  float* out = (float*)d_out;

  char* w = (char*)d_ws;
  bf16* xw = (bf16*)w;      w += (size_t)16777216 * 2;
  bf16* wqkv = (bf16*)w;    w += (size_t)3145728 * 2;
  bf16* wproj = (bf16*)w;   w += (size_t)1048576 * 2;
  bf16* qkv = (bf16*)w;     w += (size_t)50331648 * 2;
  bf16* attn = (bf16*)w;    w += (size_t)16777216 * 2;
  float* partial = (float*)w; w += (size_t)NCH * 64 * 4160 * 4;
  bf16* kvb = (bf16*)w;

  (void)hipFuncSetAttribute((const void*)gemm5<0>,
      hipFuncAttributeMaxDynamicSharedMemorySize, SMEMB);
  (void)hipFuncSetAttribute((const void*)gemm5<1>,
      hipFuncAttributeMaxDynamicSharedMemorySize, SMEMB);

  cast_kernel<<<8192, 256, 0, stream>>>(x, xw, 16777216 / 8);
  cast_kernel<<<1536, 256, 0, stream>>>(Wqkv, wqkv, 3145728 / 8);
  cast_kernel<<<512, 256, 0, stream>>>(Wproj, wproj, 1048576 / 8);

  // qkv = x @ Wqkv^T, phi fused on q,k   (16384x3072, K=1024): 64 x 24 = 1536 blocks
  gemm5<0><<<1536, 512, SMEMB, stream>>>(xw, wqkv, (void*)qkv, nullptr, 16384, 3072, 24);

  kv_kernel<<<NCH * 64, 256, 0, stream>>>(qkv, partial);
  kv_reduce_b<<<(64 * 80 * 64 + 255) / 256, 256, 0, stream>>>(partial, kvb);

  attn_mfma<<<64 * 16, 256, 0, stream>>>(qkv, kvb, attn);

  // out = attn @ Wproj^T + bproj   (16384x1024, K=1024): 64 x 8 = 512 blocks
  gemm5<1><<<512, 512, SMEMB, stream>>>(attn, wproj, (void*)out, bproj, 16384, 1024, 8);
}

// Round 6
// 256.830 us; speedup vs baseline: 1.1902x; 1.1902x over previous
//
#include <hip/hip_runtime.h>

typedef __bf16 bf16;
typedef bf16 bf16x8 __attribute__((ext_vector_type(8)));
typedef bf16 bf16x4 __attribute__((ext_vector_type(4)));
typedef float f32x4 __attribute__((ext_vector_type(4)));

#define B_ 4
#define T_ 4096
#define C_ 1024
#define EPS_ 1e-6f
#define KVTSTR 16448  // 16384 + 64 pad (breaks 32KB power-of-2 row stride)

typedef __attribute__((address_space(1))) const void* as1p;
typedef __attribute__((address_space(3))) void* as3p;

// ---------------- cast f32 -> bf16 (vectorized, 8/thread) ----------------
__global__ void cast_kernel(const float* __restrict__ in, bf16* __restrict__ out, int n8) {
  int i = blockIdx.x * blockDim.x + threadIdx.x;
  int stride = gridDim.x * blockDim.x;
  for (; i < n8; i += stride) {
    const float4* p = (const float4*)(in + (size_t)i * 8);
    float4 v0 = p[0];
    float4 v1 = p[1];
    bf16x8 o;
    o[0] = (bf16)v0.x; o[1] = (bf16)v0.y; o[2] = (bf16)v0.z; o[3] = (bf16)v0.w;
    o[4] = (bf16)v1.x; o[5] = (bf16)v1.y; o[6] = (bf16)v1.z; o[7] = (bf16)v1.w;
    *(bf16x8*)(out + (size_t)i * 8) = o;
  }
}

// ---------------- deep-pipelined NT GEMM: C = A[M][K] * B[N][K]^T ----------------
// MODE 0: q cols -> qbuf[n][1024] (phi); k,v cols -> kvt[col-1024][n] transposed (phi on k)
// MODE 1: f32 out + bias
#define BM 256
#define BN 128
#define BK 32
#define KD 1024
#define NT (KD / BK)                  // 32
#define ABYT (BM * BK * 2)            // 16384
#define BUFB ((BM + BN) * BK * 2)     // 24576
#define SMEMB (6 * BUFB)              // 147456

#define GSTEP(CURA, CURB, NXTA, NXTB, T)                                                   \
  do {                                                                                     \
    const bool pf = (T) + 5 < NT;                                                          \
    if (pf) {                                                                              \
      const int ko = ((T) + 5) * BK;                                                       \
      __builtin_amdgcn_global_load_lds((as1p)(pA0 + ko), (as3p)(smem + sb + tid * 16), 16, 0, 0);          \
      __builtin_amdgcn_global_load_lds((as1p)(pA1 + ko), (as3p)(smem + sb + 8192 + tid * 16), 16, 0, 0);   \
      __builtin_amdgcn_global_load_lds((as1p)(pB0 + ko), (as3p)(smem + sb + 16384 + tid * 16), 16, 0, 0);  \
    }                                                                                      \
    {                                                                                      \
      const bf16* Ab = (const bf16*)(smem + rb);                                           \
      const bf16* Bb = (const bf16*)(smem + rb + ABYT);                                    \
      _Pragma("unroll") for (int mi = 0; mi < 4; mi++)                                     \
          NXTA[mi] = *(const bf16x8*)(Ab + (wm * 64 + mi * 16 + fr) * 32 + fsw);           \
      _Pragma("unroll") for (int nj = 0; nj < 4; nj++)                                     \
          NXTB[nj] = *(const bf16x8*)(Bb + (wn * 64 + nj * 16 + fr) * 32 + fsw);           \
    }                                                                                      \
    __builtin_amdgcn_s_setprio(1);                                                         \
    _Pragma("unroll") for (int mi = 0; mi < 4; mi++)                                       \
        _Pragma("unroll") for (int nj = 0; nj < 4; nj++)                                   \
            acc[mi][nj] = __builtin_amdgcn_mfma_f32_16x16x32_bf16(CURA[mi], CURB[nj], acc[mi][nj], 0, 0, 0); \
    __builtin_amdgcn_s_setprio(0);                                                         \
    asm volatile("s_waitcnt lgkmcnt(0)" ::: "memory");                                     \
    if (pf) asm volatile("s_waitcnt vmcnt(9)" ::: "memory");                               \
    else    asm volatile("s_waitcnt vmcnt(0)" ::: "memory");                               \
    __builtin_amdgcn_s_barrier();                                                          \
    __builtin_amdgcn_sched_barrier(0);                                                     \
    rb += BUFB; if (rb >= SMEMB) rb -= SMEMB;                                              \
    sb += BUFB; if (sb >= SMEMB) sb -= SMEMB;                                              \
  } while (0)

template <int MODE>
__global__ __launch_bounds__(512, 1) void gemm5(
    const bf16* __restrict__ A, const bf16* __restrict__ Bm,
    void* __restrict__ Cout, const float* __restrict__ bias,
    bf16* __restrict__ kvt, int M, int N, int tiles_n) {
  extern __shared__ char smem[];
  const int tid = threadIdx.x;
  const int l = tid & 63;
  const int w = tid >> 6;
  const int wm = w >> 1;
  const int wn = w & 1;

  const int cpx = gridDim.x >> 3;
  const int bid = (blockIdx.x & 7) * cpx + (blockIdx.x >> 3);
  const int tm = (bid / tiles_n) * BM;
  const int tn = (bid % tiles_n) * BN;

  const int srow = tid >> 2;
  const int g8 = ((tid & 3) ^ ((tid >> 3) & 3)) * 8;

  const bf16* pA0 = A + (size_t)(tm + srow) * KD + g8;
  const bf16* pA1 = A + (size_t)(tm + 128 + srow) * KD + g8;
  const bf16* pB0 = Bm + (size_t)(tn + srow) * KD + g8;

  const int fr = l & 15;
  const int fc = l >> 4;
  const int fsw = (fc ^ ((fr >> 1) & 3)) * 8;

  f32x4 acc[4][4] = {};
  bf16x8 afA[4], bfA[4], afB[4], bfB[4];

#pragma unroll
  for (int kt = 0; kt < 5; kt++) {
    __builtin_amdgcn_global_load_lds((as1p)(pA0 + kt * BK), (as3p)(smem + kt * BUFB + tid * 16), 16, 0, 0);
    __builtin_amdgcn_global_load_lds((as1p)(pA1 + kt * BK), (as3p)(smem + kt * BUFB + 8192 + tid * 16), 16, 0, 0);
    __builtin_amdgcn_global_load_lds((as1p)(pB0 + kt * BK), (as3p)(smem + kt * BUFB + 16384 + tid * 16), 16, 0, 0);
  }
  asm volatile("s_waitcnt vmcnt(9)" ::: "memory");
  __builtin_amdgcn_s_barrier();
  __builtin_amdgcn_sched_barrier(0);

  {
    const bf16* Ab = (const bf16*)(smem);
    const bf16* Bb = (const bf16*)(smem + ABYT);
#pragma unroll
    for (int mi = 0; mi < 4; mi++)
      afA[mi] = *(const bf16x8*)(Ab + (wm * 64 + mi * 16 + fr) * 32 + fsw);
#pragma unroll
    for (int nj = 0; nj < 4; nj++)
      bfA[nj] = *(const bf16x8*)(Bb + (wn * 64 + nj * 16 + fr) * 32 + fsw);
  }

  int rb = BUFB;
  int sb = 5 * BUFB;
  for (int t = 0; t < NT; t += 2) {
    GSTEP(afA, bfA, afB, bfB, t);
    GSTEP(afB, bfB, afA, bfA, t + 1);
  }

  // ---------------- epilogue: C/D col = lane&15, row = (lane>>4)*4 + r ----------------
  const int crow0 = tm + wm * 64 + (l >> 4) * 4;
  const int ccol0 = tn + wn * 64 + (l & 15);
  if (MODE == 0) {
    if (tn < 1024) {
      // q block: qbuf[n][1024], phi
      bf16* qbuf = (bf16*)Cout;
#pragma unroll
      for (int mi = 0; mi < 4; mi++)
#pragma unroll
        for (int nj = 0; nj < 4; nj++) {
          const int col = ccol0 + nj * 16;
#pragma unroll
          for (int r = 0; r < 4; r++) {
            const int row = crow0 + mi * 16 + r;
            float v = acc[mi][nj][r];
            v = (v > 0.f) ? (v + 1.0f) : __expf(v);
            qbuf[(size_t)row * 1024 + col] = (bf16)v;
          }
        }
    } else {
      // k/v block: transposed write kvt[col-1024][n], phi on k (col' < 1024)
#pragma unroll
      for (int mi = 0; mi < 4; mi++)
#pragma unroll
        for (int nj = 0; nj < 4; nj++) {
          const int colp = ccol0 + nj * 16 - 1024;
          const bool isk = (colp < 1024);
          bf16x4 pk;
#pragma unroll
          for (int r = 0; r < 4; r++) {
            float v = acc[mi][nj][r];
            if (isk) v = (v > 0.f) ? (v + 1.0f) : __expf(v);
            pk[r] = (bf16)v;
          }
          const int n0 = crow0 + mi * 16;  // 4 consecutive n, 8B-aligned
          *(bf16x4*)(kvt + (size_t)colp * KVTSTR + n0) = pk;
        }
    }
  } else {
    float* Cf = (float*)Cout;
#pragma unroll
    for (int mi = 0; mi < 4; mi++)
#pragma unroll
      for (int nj = 0; nj < 4; nj++) {
        const int col = ccol0 + nj * 16;
        const float bv = bias[col];
#pragma unroll
        for (int r = 0; r < 4; r++) {
          const int row = crow0 + mi * 16 + r;
          Cf[(size_t)row * N + col] = acc[mi][nj][r] + bv;
        }
      }
  }
}

// ---------------- kvgemm: partial kv[d][m] (+ksum) per (kchunk, b, h) via MFMA ----------
// A = phi(k)^T rows of kvt (n-contiguous), B = v^T rows of kvt. No LDS, reg dbuf.
__global__ __launch_bounds__(256) void kvgemm(const bf16* __restrict__ kvt,
                                              float* __restrict__ partial) {
  const int kc = blockIdx.x >> 6;      // 0..3 (n chunk of 1024)
  const int bh = blockIdx.x & 63;
  const int b = bh >> 4, h = bh & 15;
  const int l = threadIdx.x & 63;
  const int w = threadIdx.x >> 6;      // wave -> d rows w*16..w*16+15

  const size_t nb = (size_t)b * 4096 + kc * 1024 + (l >> 4) * 8;
  const bf16* Ar = kvt + (size_t)(h * 64 + w * 16 + (l & 15)) * KVTSTR + nb;
  const bf16* Br = kvt + (size_t)(1024 + h * 64 + (l & 15)) * KVTSTR + nb;

  f32x4 acc[4] = {};
  float ks = 0.f;
  bf16x8 aC, bC[4], aN, bN[4];
  aC = *(const bf16x8*)Ar;
#pragma unroll
  for (int nj = 0; nj < 4; nj++) bC[nj] = *(const bf16x8*)(Br + (size_t)nj * 16 * KVTSTR);

  for (int it = 0; it < 32; ++it) {
    if (it + 1 < 32) {
      aN = *(const bf16x8*)(Ar + (it + 1) * 32);
#pragma unroll
      for (int nj = 0; nj < 4; nj++)
        bN[nj] = *(const bf16x8*)(Br + (size_t)nj * 16 * KVTSTR + (it + 1) * 32);
    }
#pragma unroll
    for (int i = 0; i < 8; i++) ks += (float)aC[i];
#pragma unroll
    for (int nj = 0; nj < 4; nj++)
      acc[nj] = __builtin_amdgcn_mfma_f32_16x16x32_bf16(aC, bC[nj], acc[nj], 0, 0, 0);
    aC = aN;
#pragma unroll
    for (int nj = 0; nj < 4; nj++) bC[nj] = bN[nj];
  }

  // ksum: combine the 4 k-chunk lane groups (same d = l&15)
  ks += __shfl_xor(ks, 16);
  ks += __shfl_xor(ks, 32);

  float* p = partial + (size_t)(kc * 64 + bh) * 4160;
#pragma unroll
  for (int nj = 0; nj < 4; nj++) {
    const int m = nj * 16 + (l & 15);
#pragma unroll
    for (int r = 0; r < 4; r++) {
      const int d = w * 16 + (l >> 4) * 4 + r;
      p[d * 64 + m] = acc[nj][r];
    }
  }
  if (l < 16) p[4096 + w * 16 + l] = ks;
}

// ---------------- finalize: 4 partials -> kvb[bh][80][64] bf16 ----------------
// rows 0..63: kvT[m][d]; row 64: ksum_hi[d]; row 65: ksum_lo[d]; rows 66..79: 0
__global__ void kv_finalize(const float* __restrict__ partial, bf16* __restrict__ kvb) {
  const int bh = blockIdx.x;
  for (int i = threadIdx.x; i < 80 * 64; i += 256) {
    const int row = i >> 6;
    const int dd = i & 63;
    float outv = 0.f;
    if (row < 64) {
      float s = 0.f;
#pragma unroll
      for (int kc = 0; kc < 4; kc++)
        s += partial[(size_t)(kc * 64 + bh) * 4160 + dd * 64 + row];
      outv = s;  // kv[dd][row] -> kvb[m=row][d=dd]
    } else if (row < 66) {
      float s = 0.f;
#pragma unroll
      for (int kc = 0; kc < 4; kc++)
        s += partial[(size_t)(kc * 64 + bh) * 4160 + 4096 + dd];
      bf16 hi = (bf16)s;
      outv = (row == 64) ? (float)hi : (s - (float)hi);
    }
    kvb[(size_t)bh * 5120 + row * 64 + dd] = (bf16)outv;
  }
}

// ---------------- attn out via MFMA: out[t,m] = (q[t,:].kvT[m,:]) / (q.ksum + eps) -----
__global__ __launch_bounds__(256) void attn_mfma(const bf16* __restrict__ qbuf,
                                                 const bf16* __restrict__ kvb,
                                                 bf16* __restrict__ attn) {
  const int bh = blockIdx.x >> 4;
  const int tch = blockIdx.x & 15;
  const int b = bh >> 4;
  const int h = bh & 15;
  const int lane = threadIdx.x & 63;
  const int wave = threadIdx.x >> 6;
  const int t0 = tch * 256 + wave * 64;

  const bf16* kvp = kvb + (size_t)bh * 5120;
  bf16x8 bfrag[5][2];
#pragma unroll
  for (int j = 0; j < 5; j++)
#pragma unroll
    for (int kk = 0; kk < 2; kk++)
      bfrag[j][kk] = *(const bf16x8*)(kvp + (j * 16 + (lane & 15)) * 64 + kk * 32 + (lane >> 4) * 8);

  f32x4 acc[4][5] = {};
#pragma unroll
  for (int i = 0; i < 4; i++) {
    const int t = t0 + i * 16 + (lane & 15);
    const bf16* qp = qbuf + (size_t)(b * T_ + t) * 1024 + h * 64 + (lane >> 4) * 8;
    bf16x8 a0 = *(const bf16x8*)qp;
    bf16x8 a1 = *(const bf16x8*)(qp + 32);
#pragma unroll
    for (int j = 0; j < 5; j++) {
      acc[i][j] = __builtin_amdgcn_mfma_f32_16x16x32_bf16(a0, bfrag[j][0], acc[i][j], 0, 0, 0);
      acc[i][j] = __builtin_amdgcn_mfma_f32_16x16x32_bf16(a1, bfrag[j][1], acc[i][j], 0, 0, 0);
    }
  }

#pragma unroll
  for (int i = 0; i < 4; i++) {
#pragma unroll
    for (int r = 0; r < 4; r++) {
      float hi = __shfl(acc[i][4][r], (lane & 48));
      float lo = __shfl(acc[i][4][r], (lane & 48) + 1);
      float inv = 1.0f / (hi + lo + EPS_);
      const int t = t0 + i * 16 + (lane >> 4) * 4 + r;
      bf16* op = attn + (size_t)(b * T_ + t) * 1024 + h * 64 + (lane & 15);
#pragma unroll
      for (int j = 0; j < 4; j++)
        op[j * 16] = (bf16)(acc[i][j][r] * inv);
    }
  }
}

// ---------------- launch ----------------
extern "C" void kernel_launch(void* const* d_in, const int* in_sizes, int n_in,
                              void* d_out, int out_size, void* d_ws, size_t ws_size,
                              hipStream_t stream) {
  const float* x = (const float*)d_in[0];
  const float* Wqkv = (const float*)d_in[1];
  const float* Wproj = (const float*)d_in[2];
  const float* bproj = (const float*)d_in[3];
  float* out = (float*)d_out;

  char* w = (char*)d_ws;
  bf16* xw = (bf16*)w;      w += (size_t)16777216 * 2;            // 32MB
  bf16* wqkv = (bf16*)w;    w += (size_t)3145728 * 2;             // 6MB
  bf16* wproj = (bf16*)w;   w += (size_t)1048576 * 2;             // 2MB
  bf16* qbuf = (bf16*)w;    w += (size_t)16384 * 1024 * 2;        // 32MB
  bf16* kvt = (bf16*)w;     w += (size_t)2048 * KVTSTR * 2;       // 67MB
  bf16* attnb = (bf16*)w;   w += (size_t)16384 * 1024 * 2;        // 32MB
  float* partial = (float*)w; w += (size_t)4 * 64 * 4160 * 4;     // 4.3MB
  bf16* kvb = (bf16*)w;                                           // 0.64MB

  (void)hipFuncSetAttribute((const void*)gemm5<0>,
      hipFuncAttributeMaxDynamicSharedMemorySize, SMEMB);
  (void)hipFuncSetAttribute((const void*)gemm5<1>,
      hipFuncAttributeMaxDynamicSharedMemorySize, SMEMB);

  cast_kernel<<<8192, 256, 0, stream>>>(x, xw, 16777216 / 8);
  cast_kernel<<<1536, 256, 0, stream>>>(Wqkv, wqkv, 3145728 / 8);
  cast_kernel<<<512, 256, 0, stream>>>(Wproj, wproj, 1048576 / 8);

  // qkv = x @ Wqkv^T; q->qbuf (phi), k/v->kvt transposed (phi on k)
  gemm5<0><<<1536, 512, SMEMB, stream>>>(xw, wqkv, (void*)qbuf, nullptr, kvt, 16384, 3072, 24);

  kvgemm<<<256, 256, 0, stream>>>(kvt, partial);
  kv_finalize<<<64, 256, 0, stream>>>(partial, kvb);

  attn_mfma<<<64 * 16, 256, 0, stream>>>(qbuf, kvb, attnb);

  // out = attn @ Wproj^T + bproj
  gemm5<1><<<512, 512, SMEMB, stream>>>(attnb, wproj, (void*)out, bproj, nullptr, 16384, 1024, 8);
}

// Round 7
// 228.314 us; speedup vs baseline: 1.3388x; 1.1249x over previous
//
#include <hip/hip_runtime.h>

typedef __bf16 bf16;
typedef bf16 bf16x8 __attribute__((ext_vector_type(8)));
typedef bf16 bf16x4 __attribute__((ext_vector_type(4)));
typedef float f32x4 __attribute__((ext_vector_type(4)));

#define B_ 4
#define T_ 4096
#define C_ 1024
#define EPS_ 1e-6f
#define KVTSTR 16448  // 16384 + 64 pad

typedef __attribute__((address_space(1))) const void* as1p;
typedef __attribute__((address_space(3))) void* as3p;

// ---------------- cast f32 -> bf16 (vectorized, 8/thread) ----------------
__global__ void cast_kernel(const float* __restrict__ in, bf16* __restrict__ out, int n8) {
  int i = blockIdx.x * blockDim.x + threadIdx.x;
  int stride = gridDim.x * blockDim.x;
  for (; i < n8; i += stride) {
    const float4* p = (const float4*)(in + (size_t)i * 8);
    float4 v0 = p[0];
    float4 v1 = p[1];
    bf16x8 o;
    o[0] = (bf16)v0.x; o[1] = (bf16)v0.y; o[2] = (bf16)v0.z; o[3] = (bf16)v0.w;
    o[4] = (bf16)v1.x; o[5] = (bf16)v1.y; o[6] = (bf16)v1.z; o[7] = (bf16)v1.w;
    *(bf16x8*)(out + (size_t)i * 8) = o;
  }
}

// ---------------- deep-pipelined NT GEMM: C = A[M][K] * B[N][K]^T ----------------
// 256x256 tile, 8 waves (2M x 4N, wave tile 128x64), BK=32, 4-buffer LDS ring (128KB),
// stage-3-ahead, per-wave vmcnt(4) gate, reg double-buffered fragments, 1 barrier/step.
#define BM 256
#define BN 256
#define BK 32
#define KD 1024
#define NT (KD / BK)                   // 32
#define ABYT (BM * BK * 2)             // 16384
#define BUFB (2 * ABYT)                // 32768 (A + B)
#define SMEMB (4 * BUFB)               // 131072

// One step: compute tile T from CUR regs, read tile T+1 into NXT regs (buf (T+1)&3),
// stage tile T+3 (buf (T+3)&3), gate vmcnt(4) so tile T+2 is resident at next step.
#define GSTEP(CURA, CURB, NXTA, NXTB, T)                                                       \
  do {                                                                                         \
    const bool st = (T) + 3 < NT;                                                              \
    if (st) {                                                                                  \
      const int ko = ((T) + 3) * BK;                                                           \
      char* db = smem + (((T) + 3) & 3) * BUFB;                                                \
      __builtin_amdgcn_global_load_lds((as1p)(pA0 + ko), (as3p)(db + tid * 16), 16, 0, 0);     \
      __builtin_amdgcn_global_load_lds((as1p)(pA1 + ko), (as3p)(db + 8192 + tid * 16), 16, 0, 0);   \
      __builtin_amdgcn_global_load_lds((as1p)(pB0 + ko), (as3p)(db + 16384 + tid * 16), 16, 0, 0);  \
      __builtin_amdgcn_global_load_lds((as1p)(pB1 + ko), (as3p)(db + 24576 + tid * 16), 16, 0, 0);  \
    }                                                                                          \
    if ((T) + 1 < NT) {                                                                        \
      const bf16* Ab = (const bf16*)(smem + (((T) + 1) & 3) * BUFB);                           \
      const bf16* Bb = Ab + BM * BK;                                                           \
      _Pragma("unroll") for (int mi = 0; mi < 8; mi++)                                         \
          NXTA[mi] = *(const bf16x8*)(Ab + (wm * 128 + mi * 16 + fr) * 32 + fsw);              \
      _Pragma("unroll") for (int nj = 0; nj < 4; nj++)                                         \
          NXTB[nj] = *(const bf16x8*)(Bb + (wn * 64 + nj * 16 + fr) * 32 + fsw);               \
    }                                                                                          \
    __builtin_amdgcn_s_setprio(1);                                                             \
    _Pragma("unroll") for (int mi = 0; mi < 8; mi++)                                           \
        _Pragma("unroll") for (int nj = 0; nj < 4; nj++)                                       \
            acc[mi][nj] = __builtin_amdgcn_mfma_f32_16x16x32_bf16(CURA[mi], CURB[nj], acc[mi][nj], 0, 0, 0); \
    __builtin_amdgcn_s_setprio(0);                                                             \
    asm volatile("s_waitcnt lgkmcnt(0)" ::: "memory");                                         \
    if (st) asm volatile("s_waitcnt vmcnt(4)" ::: "memory");                                   \
    else    asm volatile("s_waitcnt vmcnt(0)" ::: "memory");                                   \
    __builtin_amdgcn_s_barrier();                                                              \
    __builtin_amdgcn_sched_barrier(0);                                                         \
  } while (0)

template <int MODE>
__global__ __launch_bounds__(512, 1) void gemm6(
    const bf16* __restrict__ A, const bf16* __restrict__ Bm,
    void* __restrict__ Cout, const float* __restrict__ bias,
    bf16* __restrict__ kvt, int M, int N, int tiles_n) {
  extern __shared__ char smem[];
  const int tid = threadIdx.x;
  const int l = tid & 63;
  const int w = tid >> 6;
  const int wm = w >> 2;   // 0..1  (M: 2 x 128)
  const int wn = w & 3;    // 0..3  (N: 4 x 64)

  const int cpx = gridDim.x >> 3;
  const int bid = (blockIdx.x & 7) * cpx + (blockIdx.x >> 3);
  const int tm = (bid / tiles_n) * BM;
  const int tn = (bid % tiles_n) * BN;

  // staging: srow = tid>>2 (128 rows/load), chunk = tid&3; swizzled source chunk
  const int srow = tid >> 2;
  const int g8 = ((tid & 3) ^ ((tid >> 3) & 3)) * 8;

  const bf16* pA0 = A + (size_t)(tm + srow) * KD + g8;
  const bf16* pA1 = A + (size_t)(tm + 128 + srow) * KD + g8;
  const bf16* pB0 = Bm + (size_t)(tn + srow) * KD + g8;
  const bf16* pB1 = Bm + (size_t)(tn + 128 + srow) * KD + g8;

  // fragment read: row = base + fr, slot = fc ^ ((fr>>1)&3)
  const int fr = l & 15;
  const int fc = l >> 4;
  const int fsw = (fc ^ ((fr >> 1) & 3)) * 8;

  f32x4 acc[8][4] = {};
  bf16x8 afA[8], bfA[4], afB[8], bfB[4];

  // prologue: stage tiles 0,1,2 into bufs 0,1,2
#pragma unroll
  for (int kt = 0; kt < 3; kt++) {
    char* db = smem + kt * BUFB;
    __builtin_amdgcn_global_load_lds((as1p)(pA0 + kt * BK), (as3p)(db + tid * 16), 16, 0, 0);
    __builtin_amdgcn_global_load_lds((as1p)(pA1 + kt * BK), (as3p)(db + 8192 + tid * 16), 16, 0, 0);
    __builtin_amdgcn_global_load_lds((as1p)(pB0 + kt * BK), (as3p)(db + 16384 + tid * 16), 16, 0, 0);
    __builtin_amdgcn_global_load_lds((as1p)(pB1 + kt * BK), (as3p)(db + 24576 + tid * 16), 16, 0, 0);
  }
  asm volatile("s_waitcnt vmcnt(4)" ::: "memory");  // tiles 0,1 landed
  __builtin_amdgcn_s_barrier();
  __builtin_amdgcn_sched_barrier(0);

  // preload CUR = tile 0 (buffer 0)
  {
    const bf16* Ab = (const bf16*)(smem);
    const bf16* Bb = Ab + BM * BK;
#pragma unroll
    for (int mi = 0; mi < 8; mi++)
      afA[mi] = *(const bf16x8*)(Ab + (wm * 128 + mi * 16 + fr) * 32 + fsw);
#pragma unroll
    for (int nj = 0; nj < 4; nj++)
      bfA[nj] = *(const bf16x8*)(Bb + (wn * 64 + nj * 16 + fr) * 32 + fsw);
  }
  asm volatile("s_waitcnt lgkmcnt(0)" ::: "memory");
  __builtin_amdgcn_sched_barrier(0);

  for (int t = 0; t < NT; t += 2) {
    GSTEP(afA, bfA, afB, bfB, t);
    GSTEP(afB, bfB, afA, bfA, t + 1);
  }

  // ---------------- epilogue: C/D col = lane&15, row = (lane>>4)*4 + r ----------------
  const int crow0 = tm + wm * 128 + (l >> 4) * 4;
  const int ccol0 = tn + wn * 64 + (l & 15);
  if (MODE == 0) {
    if (tn < 1024) {
      bf16* qbuf = (bf16*)Cout;
#pragma unroll
      for (int mi = 0; mi < 8; mi++)
#pragma unroll
        for (int nj = 0; nj < 4; nj++) {
          const int col = ccol0 + nj * 16;
#pragma unroll
          for (int r = 0; r < 4; r++) {
            const int row = crow0 + mi * 16 + r;
            float v = acc[mi][nj][r];
            v = (v > 0.f) ? (v + 1.0f) : __expf(v);
            qbuf[(size_t)row * 1024 + col] = (bf16)v;
          }
        }
    } else {
#pragma unroll
      for (int mi = 0; mi < 8; mi++)
#pragma unroll
        for (int nj = 0; nj < 4; nj++) {
          const int colp = ccol0 + nj * 16 - 1024;
          const bool isk = (colp < 1024);
          bf16x4 pk;
#pragma unroll
          for (int r = 0; r < 4; r++) {
            float v = acc[mi][nj][r];
            if (isk) v = (v > 0.f) ? (v + 1.0f) : __expf(v);
            pk[r] = (bf16)v;
          }
          const int n0 = crow0 + mi * 16;
          *(bf16x4*)(kvt + (size_t)colp * KVTSTR + n0) = pk;
        }
    }
  } else {
    float* Cf = (float*)Cout;
#pragma unroll
    for (int mi = 0; mi < 8; mi++)
#pragma unroll
      for (int nj = 0; nj < 4; nj++) {
        const int col = ccol0 + nj * 16;
        const float bv = bias[col];
#pragma unroll
        for (int r = 0; r < 4; r++) {
          const int row = crow0 + mi * 16 + r;
          Cf[(size_t)row * N + col] = acc[mi][nj][r] + bv;
        }
      }
  }
}

// ---------------- kvgemm: partial kv[d][m] (+ksum) per (kchunk, b, h) via MFMA ----------
__global__ __launch_bounds__(256) void kvgemm(const bf16* __restrict__ kvt,
                                              float* __restrict__ partial) {
  const int kc = blockIdx.x >> 6;
  const int bh = blockIdx.x & 63;
  const int b = bh >> 4, h = bh & 15;
  const int l = threadIdx.x & 63;
  const int w = threadIdx.x >> 6;

  const size_t nb = (size_t)b * 4096 + kc * 1024 + (l >> 4) * 8;
  const bf16* Ar = kvt + (size_t)(h * 64 + w * 16 + (l & 15)) * KVTSTR + nb;
  const bf16* Br = kvt + (size_t)(1024 + h * 64 + (l & 15)) * KVTSTR + nb;

  f32x4 acc[4] = {};
  float ks = 0.f;
  bf16x8 aC, bC[4], aN, bN[4];
  aC = *(const bf16x8*)Ar;
#pragma unroll
  for (int nj = 0; nj < 4; nj++) bC[nj] = *(const bf16x8*)(Br + (size_t)nj * 16 * KVTSTR);

  for (int it = 0; it < 32; ++it) {
    if (it + 1 < 32) {
      aN = *(const bf16x8*)(Ar + (it + 1) * 32);
#pragma unroll
      for (int nj = 0; nj < 4; nj++)
        bN[nj] = *(const bf16x8*)(Br + (size_t)nj * 16 * KVTSTR + (it + 1) * 32);
    }
#pragma unroll
    for (int i = 0; i < 8; i++) ks += (float)aC[i];
#pragma unroll
    for (int nj = 0; nj < 4; nj++)
      acc[nj] = __builtin_amdgcn_mfma_f32_16x16x32_bf16(aC, bC[nj], acc[nj], 0, 0, 0);
    aC = aN;
#pragma unroll
    for (int nj = 0; nj < 4; nj++) bC[nj] = bN[nj];
  }

  ks += __shfl_xor(ks, 16);
  ks += __shfl_xor(ks, 32);

  float* p = partial + (size_t)(kc * 64 + bh) * 4160;
#pragma unroll
  for (int nj = 0; nj < 4; nj++) {
    const int m = nj * 16 + (l & 15);
#pragma unroll
    for (int r = 0; r < 4; r++) {
      const int d = w * 16 + (l >> 4) * 4 + r;
      p[d * 64 + m] = acc[nj][r];
    }
  }
  if (l < 16) p[4096 + w * 16 + l] = ks;
}

// ---------------- finalize: 4 partials -> kvb[bh][80][64] bf16 ----------------
__global__ void kv_finalize(const float* __restrict__ partial, bf16* __restrict__ kvb) {
  const int bh = blockIdx.x;
  for (int i = threadIdx.x; i < 80 * 64; i += 256) {
    const int row = i >> 6;
    const int dd = i & 63;
    float outv = 0.f;
    if (row < 64) {
      float s = 0.f;
#pragma unroll
      for (int kc = 0; kc < 4; kc++)
        s += partial[(size_t)(kc * 64 + bh) * 4160 + dd * 64 + row];
      outv = s;
    } else if (row < 66) {
      float s = 0.f;
#pragma unroll
      for (int kc = 0; kc < 4; kc++)
        s += partial[(size_t)(kc * 64 + bh) * 4160 + 4096 + dd];
      bf16 hi = (bf16)s;
      outv = (row == 64) ? (float)hi : (s - (float)hi);
    }
    kvb[(size_t)bh * 5120 + row * 64 + dd] = (bf16)outv;
  }
}

// ---------------- attn out via MFMA ----------------
__global__ __launch_bounds__(256) void attn_mfma(const bf16* __restrict__ qbuf,
                                                 const bf16* __restrict__ kvb,
                                                 bf16* __restrict__ attn) {
  const int bh = blockIdx.x >> 4;
  const int tch = blockIdx.x & 15;
  const int b = bh >> 4;
  const int h = bh & 15;
  const int lane = threadIdx.x & 63;
  const int wave = threadIdx.x >> 6;
  const int t0 = tch * 256 + wave * 64;

  const bf16* kvp = kvb + (size_t)bh * 5120;
  bf16x8 bfrag[5][2];
#pragma unroll
  for (int j = 0; j < 5; j++)
#pragma unroll
    for (int kk = 0; kk < 2; kk++)
      bfrag[j][kk] = *(const bf16x8*)(kvp + (j * 16 + (lane & 15)) * 64 + kk * 32 + (lane >> 4) * 8);

  f32x4 acc[4][5] = {};
#pragma unroll
  for (int i = 0; i < 4; i++) {
    const int t = t0 + i * 16 + (lane & 15);
    const bf16* qp = qbuf + (size_t)(b * T_ + t) * 1024 + h * 64 + (lane >> 4) * 8;
    bf16x8 a0 = *(const bf16x8*)qp;
    bf16x8 a1 = *(const bf16x8*)(qp + 32);
#pragma unroll
    for (int j = 0; j < 5; j++) {
      acc[i][j] = __builtin_amdgcn_mfma_f32_16x16x32_bf16(a0, bfrag[j][0], acc[i][j], 0, 0, 0);
      acc[i][j] = __builtin_amdgcn_mfma_f32_16x16x32_bf16(a1, bfrag[j][1], acc[i][j], 0, 0, 0);
    }
  }

#pragma unroll
  for (int i = 0; i < 4; i++) {
#pragma unroll
    for (int r = 0; r < 4; r++) {
      float hi = __shfl(acc[i][4][r], (lane & 48));
      float lo = __shfl(acc[i][4][r], (lane & 48) + 1);
      float inv = 1.0f / (hi + lo + EPS_);
      const int t = t0 + i * 16 + (lane >> 4) * 4 + r;
      bf16* op = attn + (size_t)(b * T_ + t) * 1024 + h * 64 + (lane & 15);
#pragma unroll
      for (int j = 0; j < 4; j++)
        op[j * 16] = (bf16)(acc[i][j][r] * inv);
    }
  }
}

// ---------------- launch ----------------
extern "C" void kernel_launch(void* const* d_in, const int* in_sizes, int n_in,
                              void* d_out, int out_size, void* d_ws, size_t ws_size,
                              hipStream_t stream) {
  const float* x = (const float*)d_in[0];
  const float* Wqkv = (const float*)d_in[1];
  const float* Wproj = (const float*)d_in[2];
  const float* bproj = (const float*)d_in[3];
  float* out = (float*)d_out;

  char* w = (char*)d_ws;
  bf16* xw = (bf16*)w;      w += (size_t)16777216 * 2;
  bf16* wqkv = (bf16*)w;    w += (size_t)3145728 * 2;
  bf16* wproj = (bf16*)w;   w += (size_t)1048576 * 2;
  bf16* qbuf = (bf16*)w;    w += (size_t)16384 * 1024 * 2;
  bf16* kvt = (bf16*)w;     w += (size_t)2048 * KVTSTR * 2;
  bf16* attnb = (bf16*)w;   w += (size_t)16384 * 1024 * 2;
  float* partial = (float*)w; w += (size_t)4 * 64 * 4160 * 4;
  bf16* kvb = (bf16*)w;

  (void)hipFuncSetAttribute((const void*)gemm6<0>,
      hipFuncAttributeMaxDynamicSharedMemorySize, SMEMB);
  (void)hipFuncSetAttribute((const void*)gemm6<1>,
      hipFuncAttributeMaxDynamicSharedMemorySize, SMEMB);

  cast_kernel<<<8192, 256, 0, stream>>>(x, xw, 16777216 / 8);
  cast_kernel<<<1536, 256, 0, stream>>>(Wqkv, wqkv, 3145728 / 8);
  cast_kernel<<<512, 256, 0, stream>>>(Wproj, wproj, 1048576 / 8);

  // qkv = x @ Wqkv^T; q->qbuf (phi), k/v->kvt transposed (phi on k)
  // grid: (16384/256) x (3072/256) = 64 x 12 = 768
  gemm6<0><<<768, 512, SMEMB, stream>>>(xw, wqkv, (void*)qbuf, nullptr, kvt, 16384, 3072, 12);

  kvgemm<<<256, 256, 0, stream>>>(kvt, partial);
  kv_finalize<<<64, 256, 0, stream>>>(partial, kvb);

  attn_mfma<<<64 * 16, 256, 0, stream>>>(qbuf, kvb, attnb);

  // out = attn @ Wproj^T + bproj   grid: 64 x 4 = 256
  gemm6<1><<<256, 512, SMEMB, stream>>>(attnb, wproj, (void*)out, bproj, nullptr, 16384, 1024, 4);
}